// Round 9
// baseline (185.451 us; speedup 1.0000x reference)
//
#include <hip/hip_runtime.h>
#include <hip/hip_bf16.h>

#define S_LEN 2048
#define NH 16
#define HD 64
#define DM 1024
#define BATCH 2
#define M_ROWS (BATCH * S_LEN)  // 4096
#define SCALE2 0.18033688011112043f  /* 0.125 * log2(e) */
#define M2FIX 8.0f

typedef float f32x4 __attribute__((ext_vector_type(4)));
typedef __bf16 bf16x8 __attribute__((ext_vector_type(8)));
typedef short short8 __attribute__((ext_vector_type(8)));

__device__ __forceinline__ unsigned short f2bf(float f) {
  unsigned u = __builtin_bit_cast(unsigned, f);
  u += 0x7FFFu + ((u >> 16) & 1u);
  return (unsigned short)(u >> 16);
}

__device__ __forceinline__ f32x4 mfma16(bf16x8 a, bf16x8 b, f32x4 c) {
  return __builtin_amdgcn_mfma_f32_16x16x32_bf16(a, b, c, 0, 0, 0);
}

__device__ __forceinline__ void gload_lds16(const void* g, void* l) {
  __builtin_amdgcn_global_load_lds(
      (const __attribute__((address_space(1))) void*)g,
      (__attribute__((address_space(3))) void*)l, 16, 0, 0);
}

// ---------------- cast x -> bf16 (vectorized) ----------------
__global__ __launch_bounds__(256) void cast_bf16_kernel(
    const float* __restrict__ in, unsigned short* __restrict__ out) {
  int i = blockIdx.x * 256 + threadIdx.x;  // each handles 8 elems
  const float4* p = (const float4*)in;
  float4 f0 = p[i * 2], f1 = p[i * 2 + 1];
  short8 o;
  o[0] = (short)f2bf(f0.x); o[1] = (short)f2bf(f0.y);
  o[2] = (short)f2bf(f0.z); o[3] = (short)f2bf(f0.w);
  o[4] = (short)f2bf(f1.x); o[5] = (short)f2bf(f1.y);
  o[6] = (short)f2bf(f1.z); o[7] = (short)f2bf(f1.w);
  ((short8*)out)[i] = o;
}

// ---------------- transpose + cast weights: Wt[n][k] = bf16(W[k][n]) ----------------
__global__ __launch_bounds__(256) void transpose_cast_kernel(
    const float* __restrict__ W0, const float* __restrict__ W1,
    const float* __restrict__ W2, const float* __restrict__ W3,
    unsigned short* __restrict__ out) {
  int z = blockIdx.z;
  const float* W = (z == 0) ? W0 : (z == 1) ? W1 : (z == 2) ? W2 : W3;
  __shared__ float tile[32][33];
  int tx = threadIdx.x & 31, ty = threadIdx.x >> 5;  // 32 x 8
  int bx = blockIdx.x * 32, by = blockIdx.y * 32;
#pragma unroll
  for (int i = 0; i < 4; ++i)
    tile[ty + i * 8][tx] = W[(size_t)(by + ty + i * 8) * DM + bx + tx];
  __syncthreads();
  unsigned short* o = out + (size_t)z * DM * DM;
#pragma unroll
  for (int i = 0; i < 4; ++i)
    o[(size_t)(bx + ty + i * 8) * DM + by + tx] = f2bf(tile[tx][ty + i * 8]);
}

// ---------------- GEMM: C[m][n] = sum_k A[m][k] * Bt[n][k] --------------------
// Triple-buffered staging, counted vmcnt(4), one barrier per K-step.
// MODE 0: QKV fused (N=3072). Q pre-scaled by SCALE2; V written transposed per
//         head via LDS transpose: Vt[((b*16+h)*64+d)*2048 + s].
// MODE 1: f32 out (single buffer), bias0.
template <int MODE>
__global__ __launch_bounds__(256) void gemm_bt_kernel(
    const unsigned short* __restrict__ A, const unsigned short* __restrict__ Bt,
    void* __restrict__ Cptr, const float* __restrict__ bias0,
    const float* __restrict__ bias1, const float* __restrict__ bias2,
    int M, int N, int K) {
  __shared__ __align__(16) unsigned short Sbuf[2][3][4096];  // As | Bs (contiguous)
  unsigned short (*As)[4096] = Sbuf[0];
  unsigned short (*Bs)[4096] = Sbuf[1];
  const int t = threadIdx.x, lane = t & 63;
  const int wid = t >> 6, wr = wid >> 1, wc = wid & 1;
  const int r16 = lane & 15, g = lane >> 4;
  const int m0 = blockIdx.y * 128, n0 = blockIdx.x * 128;
  const int nk = K >> 5;

  const int n1 = t, n2 = t + 256;
  const int r1g = t >> 2, c1g = (t & 3) * 8;
  const int r2g = (t + 256) >> 2;

  const unsigned short* ap1 = A + (size_t)(m0 + r1g) * K + c1g;
  const unsigned short* ap2 = A + (size_t)(m0 + r2g) * K + c1g;
  const unsigned short* bp1 = Bt + (size_t)(n0 + r1g) * K + c1g;
  const unsigned short* bp2 = Bt + (size_t)(n0 + r2g) * K + c1g;

#define GSTAGE(s)                          \
  gload_lds16(ap1, &As[s][n1 * 8]);        \
  gload_lds16(bp1, &Bs[s][n1 * 8]);        \
  gload_lds16(ap2, &As[s][n2 * 8]);        \
  gload_lds16(bp2, &Bs[s][n2 * 8]);        \
  ap1 += 32; ap2 += 32; bp1 += 32; bp2 += 32;

  f32x4 acc[4][4] = {};

  GSTAGE(0);
  GSTAGE(1);

  for (int kt = 0; kt < nk; ++kt) {
    const int cs = kt % 3;
    if (kt + 1 < nk) {
      asm volatile("s_waitcnt vmcnt(4)" ::: "memory");
    } else {
      asm volatile("s_waitcnt vmcnt(0)" ::: "memory");
    }
    __builtin_amdgcn_s_barrier();
    if (kt + 2 < nk) { GSTAGE((kt + 2) % 3); }

    bf16x8 af[4], bfr[4];
#pragma unroll
    for (int mi = 0; mi < 4; ++mi)
      af[mi] = *(const bf16x8*)&As[cs][(wr * 64 + mi * 16 + r16) * 32 + g * 8];
#pragma unroll
    for (int ni = 0; ni < 4; ++ni)
      bfr[ni] = *(const bf16x8*)&Bs[cs][(wc * 64 + ni * 16 + r16) * 32 + g * 8];
    __builtin_amdgcn_s_setprio(1);
#pragma unroll
    for (int mi = 0; mi < 4; ++mi)
#pragma unroll
      for (int ni = 0; ni < 4; ++ni)
        acc[mi][ni] = mfma16(af[mi], bfr[ni], acc[mi][ni]);
    __builtin_amdgcn_s_setprio(0);
  }
#undef GSTAGE

  if (MODE == 0) {
    unsigned short* Cb = (unsigned short*)Cptr;
    const int buf = n0 >> 10;  // whole block lies in one of Q/K/V (128 | 1024)
    if (buf < 2) {
      const float* bp = buf ? bias1 : bias0;
      const float sc = buf ? 1.0f : SCALE2;  // pre-scale Q for attn
#pragma unroll
      for (int ni = 0; ni < 4; ++ni) {
        int cn = (n0 & 1023) + wc * 64 + ni * 16 + r16;
        float bv = bp[cn];
#pragma unroll
        for (int mi = 0; mi < 4; ++mi) {
          int rowb = m0 + wr * 64 + mi * 16 + 4 * g;
#pragma unroll
          for (int j = 0; j < 4; ++j)
            Cb[(size_t)buf * 4194304u + (size_t)(rowb + j) * 1024 + cn] =
                __builtin_bit_cast(unsigned short, (__bf16)((acc[mi][ni][j] + bv) * sc));
        }
      }
    } else {
      // V: transpose the 128(s) x 128(hd) tile through LDS, then write V^T with
      // 16B stores contiguous along s.
      unsigned short* T = &Sbuf[0][0][0];  // 24576 shorts >= 128*136 = 17408
      __syncthreads();  // all waves done with staging LDS
#pragma unroll
      for (int ni = 0; ni < 4; ++ni) {
        int cnl = wc * 64 + ni * 16 + r16;
        float bv = bias2[(n0 & 1023) + cnl];
#pragma unroll
        for (int mi = 0; mi < 4; ++mi) {
          int sl = wr * 64 + mi * 16 + 4 * g;
          union { __bf16 h4[4]; uint2 u; } cv;
#pragma unroll
          for (int j = 0; j < 4; ++j) cv.h4[j] = (__bf16)(acc[mi][ni][j] + bv);
          *(uint2*)&T[cnl * 136 + sl] = cv.u;
        }
      }
      __syncthreads();
      const int bb = m0 >> 11, s0g = m0 & 2047;
      unsigned short* Vt = Cb + 8388608u;
#pragma unroll
      for (int p = 0; p < 8; ++p) {
        int idx = p * 256 + t;
        int cnl = idx >> 4, sch = idx & 15;
        int cng = (n0 & 1023) + cnl;
        int hh = cng >> 6, d = cng & 63;
        short8 v = *(const short8*)&T[cnl * 136 + sch * 8];
        *(short8*)&Vt[(((size_t)((bb * 16 + hh) * 64 + d)) << 11) + s0g + sch * 8] = v;
      }
    }
  } else {
    float* Cf = (float*)Cptr;
#pragma unroll
    for (int ni = 0; ni < 4; ++ni) {
      int col = n0 + wc * 64 + ni * 16 + r16;
      float bv = bias0[col];
#pragma unroll
      for (int mi = 0; mi < 4; ++mi) {
        int rowb = m0 + wr * 64 + mi * 16 + 4 * g;
#pragma unroll
        for (int j = 0; j < 4; ++j)
          Cf[(size_t)(rowb + j) * N + col] = acc[mi][ni][j] + bv;
      }
    }
  }
}

// ---------------- flash attention v9: barrier-free direct-load ----------------
// grid 512 x 256 (4 waves/block). Each WAVE is fully independent: it owns one
// 16-row q-group and streams K / V^T MFMA fragments DIRECTLY global->VGPR
// (L1/L2-served; per-XCD working set 2MB < 4MB L2 via the XCD decode). No K/V
// LDS, no barriers, no vmcnt discipline -- compiler pipelines loads freely.
// Balance: wave processes q-groups {pair, 127-pair} sequentially = exactly 33
// KV 64-tiles for every wave. O^T formulation (lane owns q = r16).
// Fixed-shift exp2 softmax (m=8, exact). Softmax denominator computed on the
// MATRIX pipe: lacc = mfma(ones, P-frag) gives Sum_k P^T[k][q] in every row ->
// no VALU adds, no epilogue shuffle reduce.
__global__ __launch_bounds__(256) void attn_kernel(
    const unsigned short* __restrict__ Qm, const unsigned short* __restrict__ Km,
    const unsigned short* __restrict__ VtG, unsigned short* __restrict__ Om) {
  const int t = threadIdx.x, lane = t & 63, w = t >> 6;
  const int r16 = lane & 15, fg = lane >> 4;
  const int bid = blockIdx.x;
  const int xk = bid & 7, slot = bid >> 3;   // slot 0..63
  const int grp = xk * 4 + (slot >> 4);      // (b,h) group 0..31, fixed per XCD
  const int h = grp & 15, b = grp >> 4;
  const int pair = (slot & 15) * 4 + w;      // q-group pair index 0..63

  __shared__ __align__(16) unsigned short Pl[4][1152];  // per-wave P bounce
  unsigned short* Pw = Pl[w];
  unsigned* Pw32 = (unsigned*)Pw;

  const unsigned short* Kb = Km + (size_t)(b * S_LEN) * DM + h * HD;
  const unsigned short* Vb = VtG + (size_t)((b * NH + h) * HD) * S_LEN;

  bf16x8 ones;
#pragma unroll
  for (int e = 0; e < 8; ++e) ones[e] = (__bf16)1.0f;

  for (int half = 0; half < 2; ++half) {
    const int qg = half ? 127 - pair : pair;  // q-group 0..127
    const int qrow = qg * 16 + r16;           // this lane's global q row
    const int ntk = (qg >> 2) + 1;            // KV 64-tiles needed
    const int diag = qg >> 2;                 // masked tile index
    const int qrel = ((qg & 3) << 4) + r16;   // q position within diag tile

    const unsigned short* Qp = Qm + (size_t)(b * S_LEN + qrow) * DM + h * HD;
    bf16x8 qf0 = *(const bf16x8*)(Qp + fg * 8);
    bf16x8 qf1 = *(const bf16x8*)(Qp + 32 + fg * 8);

    f32x4 oacc[4] = {};
    f32x4 lacc = {};  // softmax denominator via ones-MFMA

    for (int kt = 0; kt < ntk; ++kt) {
      const int kv0 = kt * 64;
      const unsigned short* Kt = Kb + (size_t)kv0 * DM;
      const unsigned short* Vt0 = Vb + kv0;

      // QK^T: St[kv = ni*16+4fg+j][q = r16], K fragments straight from L1/L2
      f32x4 st[4];
#pragma unroll
      for (int ni = 0; ni < 4; ++ni) {
        const unsigned short* kr = Kt + (size_t)(ni * 16 + r16) * DM;
        bf16x8 kf0 = *(const bf16x8*)(kr + fg * 8);
        bf16x8 kf1 = *(const bf16x8*)(kr + 32 + fg * 8);
        f32x4 z = {};
        __builtin_amdgcn_s_setprio(1);
        st[ni] = mfma16(kf1, qf1, mfma16(kf0, qf0, z));
        __builtin_amdgcn_s_setprio(0);
      }

      // fixed-shift softmax weights: p = exp2(s2 - 8) (exact shift-invariance)
      float p[4][4];
#pragma unroll
      for (int ni = 0; ni < 4; ++ni)
#pragma unroll
        for (int j = 0; j < 4; ++j)
          p[ni][j] = __builtin_amdgcn_exp2f(st[ni][j] - M2FIX);
      if (kt == diag) {  // causal mask on the diagonal tile
#pragma unroll
        for (int ni = 0; ni < 4; ++ni)
#pragma unroll
          for (int j = 0; j < 4; ++j) {
            int kvl = ni * 16 + 4 * fg + j;
            if (kvl > qrel) p[ni][j] = 0.f;
          }
      }

      // pack P -> per-wave LDS (stride 72 shorts), read back as B-fragments
#pragma unroll
      for (int ni = 0; ni < 4; ++ni) {
        union { __bf16 hh[4]; uint2 u2; } cv;
        cv.hh[0] = (__bf16)p[ni][0];
        cv.hh[1] = (__bf16)p[ni][1];
        cv.hh[2] = (__bf16)p[ni][2];
        cv.hh[3] = (__bf16)p[ni][3];
        *(uint2*)&Pw32[r16 * 36 + ni * 8 + 2 * fg] = cv.u2;
      }
      bf16x8 pf0 = *(const bf16x8*)&Pw[r16 * 72 + fg * 8];
      bf16x8 pf1 = *(const bf16x8*)&Pw[r16 * 72 + 32 + fg * 8];

      // denominator on the matrix pipe: every C row = Sum_k P^T[k][q=r16]
      lacc = mfma16(ones, pf1, mfma16(ones, pf0, lacc));

      // PV: O^T[d = di*16+4fg+j][q = r16] += V^T[d][kv] P^T[kv][q]
      __builtin_amdgcn_s_setprio(1);
#pragma unroll
      for (int di = 0; di < 4; ++di) {
        const unsigned short* vr = Vt0 + (size_t)(di * 16 + r16) * S_LEN;
        bf16x8 vf0 = *(const bf16x8*)(vr + fg * 8);
        bf16x8 vf1 = *(const bf16x8*)(vr + 32 + fg * 8);
        oacc[di] = mfma16(vf0, pf0, oacc[di]);
        oacc[di] = mfma16(vf1, pf1, oacc[di]);
      }
      __builtin_amdgcn_s_setprio(0);
    }

    // epilogue: lacc[0] is already the full denominator for q = r16
    float li = 1.0f / lacc[0];
    unsigned short* op = Om + (size_t)(b * S_LEN + qrow) * DM + h * HD;
#pragma unroll
    for (int di = 0; di < 4; ++di) {
      union { __bf16 hh[4]; uint2 u2; } ov;
      ov.hh[0] = (__bf16)(oacc[di][0] * li);
      ov.hh[1] = (__bf16)(oacc[di][1] * li);
      ov.hh[2] = (__bf16)(oacc[di][2] * li);
      ov.hh[3] = (__bf16)(oacc[di][3] * li);
      *(uint2*)(op + di * 16 + 4 * fg) = ov.u2;
    }
  }
}

extern "C" void kernel_launch(void* const* d_in, const int* in_sizes, int n_in,
                              void* d_out, int out_size, void* d_ws, size_t ws_size,
                              hipStream_t stream) {
  (void)in_sizes; (void)n_in; (void)out_size; (void)ws_size;
  const float* x  = (const float*)d_in[0];
  const float* WQ = (const float*)d_in[1];
  const float* WK = (const float*)d_in[2];
  const float* WV = (const float*)d_in[3];
  const float* WO = (const float*)d_in[4];
  const float* bQ = (const float*)d_in[5];
  const float* bK = (const float*)d_in[6];
  const float* bV = (const float*)d_in[7];
  const float* bO = (const float*)d_in[8];

  char* ws = (char*)d_ws;
  unsigned short* xb  = (unsigned short*)(ws);               // 8 MiB (x bf16)
  unsigned short* wt  = (unsigned short*)(ws + (8u << 20));  // 8 MiB (Wq|Wk|Wv|Wo)^T
  unsigned short* qb  = (unsigned short*)(ws + (16u << 20)); // 24 MiB (Q | K | V^T)
  unsigned short* hsb = (unsigned short*)(ws + (40u << 20)); // 8 MiB (attn out)

  cast_bf16_kernel<<<2048, 256, 0, stream>>>(x, xb);
  transpose_cast_kernel<<<dim3(32, 32, 4), 256, 0, stream>>>(WQ, WK, WV, WO, wt);
  // fused QKV projection: N = 3072; Q pre-scaled; V^T via LDS-transposed epilogue
  gemm_bt_kernel<0><<<dim3(24, 32), 256, 0, stream>>>(
      xb, wt, (void*)qb, bQ, bK, bV, M_ROWS, 3072, DM);
  attn_kernel<<<512, 256, 0, stream>>>(qb, qb + 4194304u, qb + 8388608u, hsb);
  // output projection: f32 out
  gemm_bt_kernel<1><<<dim3(8, 32), 256, 0, stream>>>(
      hsb, wt + 3u * 1048576u, d_out, bO, nullptr, nullptr, M_ROWS, DM, DM);
}

// Round 10
// 120.005 us; speedup vs baseline: 1.5454x; 1.5454x over previous
//
#include <hip/hip_runtime.h>
#include <hip/hip_bf16.h>

#define S_LEN 2048
#define NH 16
#define HD 64
#define DM 1024
#define BATCH 2
#define M_ROWS (BATCH * S_LEN)  // 4096
#define SCALE2 0.18033688011112043f  /* 0.125 * log2(e) */
#define M2FIX 8.0f

typedef float f32x4 __attribute__((ext_vector_type(4)));
typedef __bf16 bf16x8 __attribute__((ext_vector_type(8)));
typedef short short8 __attribute__((ext_vector_type(8)));

__device__ __forceinline__ unsigned short f2bf(float f) {
  unsigned u = __builtin_bit_cast(unsigned, f);
  u += 0x7FFFu + ((u >> 16) & 1u);
  return (unsigned short)(u >> 16);
}

__device__ __forceinline__ f32x4 mfma16(bf16x8 a, bf16x8 b, f32x4 c) {
  return __builtin_amdgcn_mfma_f32_16x16x32_bf16(a, b, c, 0, 0, 0);
}

__device__ __forceinline__ void gload_lds16(const void* g, void* l) {
  __builtin_amdgcn_global_load_lds(
      (const __attribute__((address_space(1))) void*)g,
      (__attribute__((address_space(3))) void*)l, 16, 0, 0);
}

// ---------------- cast x -> bf16 (vectorized) ----------------
__global__ __launch_bounds__(256) void cast_bf16_kernel(
    const float* __restrict__ in, unsigned short* __restrict__ out) {
  int i = blockIdx.x * 256 + threadIdx.x;  // each handles 8 elems
  const float4* p = (const float4*)in;
  float4 f0 = p[i * 2], f1 = p[i * 2 + 1];
  short8 o;
  o[0] = (short)f2bf(f0.x); o[1] = (short)f2bf(f0.y);
  o[2] = (short)f2bf(f0.z); o[3] = (short)f2bf(f0.w);
  o[4] = (short)f2bf(f1.x); o[5] = (short)f2bf(f1.y);
  o[6] = (short)f2bf(f1.z); o[7] = (short)f2bf(f1.w);
  ((short8*)out)[i] = o;
}

// ---------------- transpose + cast weights: Wt[n][k] = bf16(W[k][n]) ----------------
__global__ __launch_bounds__(256) void transpose_cast_kernel(
    const float* __restrict__ W0, const float* __restrict__ W1,
    const float* __restrict__ W2, const float* __restrict__ W3,
    unsigned short* __restrict__ out) {
  int z = blockIdx.z;
  const float* W = (z == 0) ? W0 : (z == 1) ? W1 : (z == 2) ? W2 : W3;
  __shared__ float tile[32][33];
  int tx = threadIdx.x & 31, ty = threadIdx.x >> 5;  // 32 x 8
  int bx = blockIdx.x * 32, by = blockIdx.y * 32;
#pragma unroll
  for (int i = 0; i < 4; ++i)
    tile[ty + i * 8][tx] = W[(size_t)(by + ty + i * 8) * DM + bx + tx];
  __syncthreads();
  unsigned short* o = out + (size_t)z * DM * DM;
#pragma unroll
  for (int i = 0; i < 4; ++i)
    o[(size_t)(bx + ty + i * 8) * DM + by + tx] = f2bf(tile[tx][ty + i * 8]);
}

// ---------------- GEMM: C[m][n] = sum_k A[m][k] * Bt[n][k] --------------------
// Triple-buffered staging, counted vmcnt(4), one barrier per K-step.
// MODE 0: QKV fused (N=3072). Q pre-scaled by SCALE2; V written transposed per
//         head via LDS transpose: Vt[((b*16+h)*64+d)*2048 + s].
// MODE 1: f32 out (single buffer), bias0.
template <int MODE>
__global__ __launch_bounds__(256) void gemm_bt_kernel(
    const unsigned short* __restrict__ A, const unsigned short* __restrict__ Bt,
    void* __restrict__ Cptr, const float* __restrict__ bias0,
    const float* __restrict__ bias1, const float* __restrict__ bias2,
    int M, int N, int K) {
  __shared__ __align__(16) unsigned short Sbuf[2][3][4096];  // As | Bs (contiguous)
  unsigned short (*As)[4096] = Sbuf[0];
  unsigned short (*Bs)[4096] = Sbuf[1];
  const int t = threadIdx.x, lane = t & 63;
  const int wid = t >> 6, wr = wid >> 1, wc = wid & 1;
  const int r16 = lane & 15, g = lane >> 4;
  const int m0 = blockIdx.y * 128, n0 = blockIdx.x * 128;
  const int nk = K >> 5;

  const int n1 = t, n2 = t + 256;
  const int r1g = t >> 2, c1g = (t & 3) * 8;
  const int r2g = (t + 256) >> 2;

  const unsigned short* ap1 = A + (size_t)(m0 + r1g) * K + c1g;
  const unsigned short* ap2 = A + (size_t)(m0 + r2g) * K + c1g;
  const unsigned short* bp1 = Bt + (size_t)(n0 + r1g) * K + c1g;
  const unsigned short* bp2 = Bt + (size_t)(n0 + r2g) * K + c1g;

#define GSTAGE(s)                          \
  gload_lds16(ap1, &As[s][n1 * 8]);        \
  gload_lds16(bp1, &Bs[s][n1 * 8]);        \
  gload_lds16(ap2, &As[s][n2 * 8]);        \
  gload_lds16(bp2, &Bs[s][n2 * 8]);        \
  ap1 += 32; ap2 += 32; bp1 += 32; bp2 += 32;

  f32x4 acc[4][4] = {};

  GSTAGE(0);
  GSTAGE(1);

  for (int kt = 0; kt < nk; ++kt) {
    const int cs = kt % 3;
    if (kt + 1 < nk) {
      asm volatile("s_waitcnt vmcnt(4)" ::: "memory");
    } else {
      asm volatile("s_waitcnt vmcnt(0)" ::: "memory");
    }
    __builtin_amdgcn_s_barrier();
    if (kt + 2 < nk) { GSTAGE((kt + 2) % 3); }

    bf16x8 af[4], bfr[4];
#pragma unroll
    for (int mi = 0; mi < 4; ++mi)
      af[mi] = *(const bf16x8*)&As[cs][(wr * 64 + mi * 16 + r16) * 32 + g * 8];
#pragma unroll
    for (int ni = 0; ni < 4; ++ni)
      bfr[ni] = *(const bf16x8*)&Bs[cs][(wc * 64 + ni * 16 + r16) * 32 + g * 8];
    __builtin_amdgcn_s_setprio(1);
#pragma unroll
    for (int mi = 0; mi < 4; ++mi)
#pragma unroll
      for (int ni = 0; ni < 4; ++ni)
        acc[mi][ni] = mfma16(af[mi], bfr[ni], acc[mi][ni]);
    __builtin_amdgcn_s_setprio(0);
  }
#undef GSTAGE

  if (MODE == 0) {
    unsigned short* Cb = (unsigned short*)Cptr;
    const int buf = n0 >> 10;  // whole block lies in one of Q/K/V (128 | 1024)
    if (buf < 2) {
      const float* bp = buf ? bias1 : bias0;
      const float sc = buf ? 1.0f : SCALE2;  // pre-scale Q for attn
#pragma unroll
      for (int ni = 0; ni < 4; ++ni) {
        int cn = (n0 & 1023) + wc * 64 + ni * 16 + r16;
        float bv = bp[cn];
#pragma unroll
        for (int mi = 0; mi < 4; ++mi) {
          int rowb = m0 + wr * 64 + mi * 16 + 4 * g;
#pragma unroll
          for (int j = 0; j < 4; ++j)
            Cb[(size_t)buf * 4194304u + (size_t)(rowb + j) * 1024 + cn] =
                __builtin_bit_cast(unsigned short, (__bf16)((acc[mi][ni][j] + bv) * sc));
        }
      }
    } else {
      // V: transpose the 128(s) x 128(hd) tile through LDS, then write V^T with
      // 16B stores contiguous along s.
      unsigned short* T = &Sbuf[0][0][0];  // 24576 shorts >= 128*136 = 17408
      __syncthreads();  // all waves done with staging LDS
#pragma unroll
      for (int ni = 0; ni < 4; ++ni) {
        int cnl = wc * 64 + ni * 16 + r16;
        float bv = bias2[(n0 & 1023) + cnl];
#pragma unroll
        for (int mi = 0; mi < 4; ++mi) {
          int sl = wr * 64 + mi * 16 + 4 * g;
          union { __bf16 h4[4]; uint2 u; } cv;
#pragma unroll
          for (int j = 0; j < 4; ++j) cv.h4[j] = (__bf16)(acc[mi][ni][j] + bv);
          *(uint2*)&T[cnl * 136 + sl] = cv.u;
        }
      }
      __syncthreads();
      const int bb = m0 >> 11, s0g = m0 & 2047;
      unsigned short* Vt = Cb + 8388608u;
#pragma unroll
      for (int p = 0; p < 8; ++p) {
        int idx = p * 256 + t;
        int cnl = idx >> 4, sch = idx & 15;
        int cng = (n0 & 1023) + cnl;
        int hh = cng >> 6, d = cng & 63;
        short8 v = *(const short8*)&T[cnl * 136 + sch * 8];
        *(short8*)&Vt[(((size_t)((bb * 16 + hh) * 64 + d)) << 11) + s0g + sch * 8] = v;
      }
    }
  } else {
    float* Cf = (float*)Cptr;
#pragma unroll
    for (int ni = 0; ni < 4; ++ni) {
      int col = n0 + wc * 64 + ni * 16 + r16;
      float bv = bias0[col];
#pragma unroll
      for (int mi = 0; mi < 4; ++mi) {
        int rowb = m0 + wr * 64 + mi * 16 + 4 * g;
#pragma unroll
        for (int j = 0; j < 4; ++j)
          Cf[(size_t)(rowb + j) * N + col] = acc[mi][ni][j] + bv;
      }
    }
  }
}

// ---------------- flash attention v10: occupancy-first single-buffer ----------------
// grid 1024 x 256 (4 waves). One 64-row q-tile per block, iters = qt+1
// (imbalanced); balance comes from 4 co-resident blocks/CU (LDS 25.2KB,
// single-buffered K/V) with adjacent bids carrying complementary qt (pairs sum
// to 31) so each CU's resident mix averages out; shortest blocks last -> tiny
// tail. XCD decode: 4 (b,h) groups per XCD -> K/V 2MB L2-resident.
// O^T formulation (lane owns q = r16). Fixed-shift exp2 softmax (m=8, exact).
// Softmax denominator on the matrix pipe (ones-MFMA, r9-validated).
__global__ __launch_bounds__(256) void attn_kernel(
    const unsigned short* __restrict__ Qm, const unsigned short* __restrict__ Km,
    const unsigned short* __restrict__ VtG, unsigned short* __restrict__ Om) {
  const int t = threadIdx.x, lane = t & 63, w = t >> 6;
  const int r16 = lane & 15, g = lane >> 4;
  const int bid = blockIdx.x;
  const int xk = bid & 7, s = bid >> 3;       // s 0..127 per XCD stream
  const int grp = xk * 4 + (s >> 5);          // (b,h) group, 4 per XCD
  const int ss = s & 31;
  const int qt = (ss & 1) ? (ss >> 1) : (31 - (ss >> 1));  // 31,0,30,1,...
  const int h = grp & 15, b = grp >> 4;

  __shared__ __align__(16) unsigned short Ks[4096];  // [64 kv][64 d] (swizzled)
  __shared__ __align__(16) unsigned short Vs[4096];  // [64 d][64 kv] (swizzled)
  __shared__ __align__(16) unsigned short Pl[4][1152];

  const unsigned short* Kbase = Km + (size_t)(b * S_LEN) * DM + h * HD;
  const unsigned short* Vbase = VtG + (size_t)((b * NH + h) * HD) * S_LEN;

  // staging: chunk n (0..511): row n>>3, lds linear, global chunk (n&7)^(row&7)
  const int n1 = t, n2 = t + 256;
  const int r1 = n1 >> 3, c1 = ((n1 & 7) ^ (r1 & 7)) * 8;
  const int r2 = n2 >> 3, c2 = ((n2 & 7) ^ (r2 & 7)) * 8;
  const int sx = r16 & 7;  // read-side XOR
  const int qloc = w * 16 + r16;
  const int q0 = qt * 64;

  unsigned short* Pw = Pl[w];
  unsigned* Pw32 = (unsigned*)Pw;

  const unsigned short* Qp = Qm + (size_t)(b * S_LEN + q0 + qloc) * DM + h * HD;
  bf16x8 qf0 = *(const bf16x8*)(Qp + g * 8);
  bf16x8 qf1 = *(const bf16x8*)(Qp + 32 + g * 8);

  bf16x8 ones;
#pragma unroll
  for (int e = 0; e < 8; ++e) ones[e] = (__bf16)1.0f;

  f32x4 oacc[4] = {};
  f32x4 lacc = {};  // denominator via ones-MFMA
  const int ntk = qt + 1;

  const unsigned short* kp1 = Kbase + (size_t)r1 * DM + c1;
  const unsigned short* kp2 = Kbase + (size_t)r2 * DM + c2;
  const unsigned short* vp1 = Vbase + (size_t)r1 * S_LEN + c1;
  const unsigned short* vp2 = Vbase + (size_t)r2 * S_LEN + c2;

  for (int kt = 0; kt < ntk; ++kt) {
    // stage current tile (single buffer)
    gload_lds16(kp1, &Ks[n1 * 8]);
    gload_lds16(kp2, &Ks[n2 * 8]);
    gload_lds16(vp1, &Vs[n1 * 8]);
    gload_lds16(vp2, &Vs[n2 * 8]);
    kp1 += 64 * DM; kp2 += 64 * DM; vp1 += 64; vp2 += 64;
    asm volatile("s_waitcnt vmcnt(0)" ::: "memory");
    __builtin_amdgcn_s_barrier();  // all waves' stages landed

    // QK^T: St[kv = ni*16+4g+j][q = r16]  (log2-domain scores)
    f32x4 st[4];
#pragma unroll
    for (int ni = 0; ni < 4; ++ni) {
      int row = ni * 16 + r16;
      f32x4 z = {};
      bf16x8 kf0 = *(const bf16x8*)&Ks[row * 64 + ((g ^ sx) * 8)];
      bf16x8 kf1 = *(const bf16x8*)&Ks[row * 64 + (((4 + g) ^ sx) * 8)];
      __builtin_amdgcn_s_setprio(1);
      st[ni] = mfma16(kf1, qf1, mfma16(kf0, qf0, z));
      __builtin_amdgcn_s_setprio(0);
    }

    // fixed-shift softmax weights: p = exp2(s2 - 8) (exact shift-invariance)
    float p[4][4];
#pragma unroll
    for (int ni = 0; ni < 4; ++ni)
#pragma unroll
      for (int j = 0; j < 4; ++j)
        p[ni][j] = __builtin_amdgcn_exp2f(st[ni][j] - M2FIX);
    if (kt == qt) {  // causal mask on the diagonal tile
#pragma unroll
      for (int ni = 0; ni < 4; ++ni)
#pragma unroll
        for (int j = 0; j < 4; ++j) {
          int kvl = ni * 16 + 4 * g + j;
          if (kvl > qloc) p[ni][j] = 0.f;
        }
    }

    // pack P -> per-wave LDS (stride 72 shorts), read back as B-fragments
#pragma unroll
    for (int ni = 0; ni < 4; ++ni) {
      union { __bf16 hh[4]; uint2 u2; } cv;
      cv.hh[0] = (__bf16)p[ni][0];
      cv.hh[1] = (__bf16)p[ni][1];
      cv.hh[2] = (__bf16)p[ni][2];
      cv.hh[3] = (__bf16)p[ni][3];
      *(uint2*)&Pw32[r16 * 36 + ni * 8 + 2 * g] = cv.u2;
    }
    bf16x8 pf0 = *(const bf16x8*)&Pw[r16 * 72 + g * 8];
    bf16x8 pf1 = *(const bf16x8*)&Pw[r16 * 72 + 32 + g * 8];

    // denominator on the matrix pipe: every C row = Sum_k P^T[k][q=r16]
    lacc = mfma16(ones, pf1, mfma16(ones, pf0, lacc));

    // PV: O^T[d = di*16+4g+j][q = r16] += V^T[d][kv] P^T[kv][q]
    __builtin_amdgcn_s_setprio(1);
#pragma unroll
    for (int di = 0; di < 4; ++di) {
      int row = di * 16 + r16;
      bf16x8 vf0 = *(const bf16x8*)&Vs[row * 64 + ((g ^ sx) * 8)];
      bf16x8 vf1 = *(const bf16x8*)&Vs[row * 64 + (((4 + g) ^ sx) * 8)];
      oacc[di] = mfma16(vf0, pf0, oacc[di]);
      oacc[di] = mfma16(vf1, pf1, oacc[di]);
    }
    __builtin_amdgcn_s_setprio(0);

    __builtin_amdgcn_s_barrier();  // all reads done before next stage overwrites
  }

  // epilogue: lacc[0] is the full denominator for q = r16 (no shuffles needed)
  float li = 1.0f / lacc[0];
  unsigned short* op = Om + (size_t)(b * S_LEN + q0 + qloc) * DM + h * HD;
#pragma unroll
  for (int di = 0; di < 4; ++di) {
    union { __bf16 hh[4]; uint2 u2; } ov;
    ov.hh[0] = (__bf16)(oacc[di][0] * li);
    ov.hh[1] = (__bf16)(oacc[di][1] * li);
    ov.hh[2] = (__bf16)(oacc[di][2] * li);
    ov.hh[3] = (__bf16)(oacc[di][3] * li);
    *(uint2*)(op + di * 16 + 4 * g) = ov.u2;
  }
}

extern "C" void kernel_launch(void* const* d_in, const int* in_sizes, int n_in,
                              void* d_out, int out_size, void* d_ws, size_t ws_size,
                              hipStream_t stream) {
  (void)in_sizes; (void)n_in; (void)out_size; (void)ws_size;
  const float* x  = (const float*)d_in[0];
  const float* WQ = (const float*)d_in[1];
  const float* WK = (const float*)d_in[2];
  const float* WV = (const float*)d_in[3];
  const float* WO = (const float*)d_in[4];
  const float* bQ = (const float*)d_in[5];
  const float* bK = (const float*)d_in[6];
  const float* bV = (const float*)d_in[7];
  const float* bO = (const float*)d_in[8];

  char* ws = (char*)d_ws;
  unsigned short* xb  = (unsigned short*)(ws);               // 8 MiB (x bf16)
  unsigned short* wt  = (unsigned short*)(ws + (8u << 20));  // 8 MiB (Wq|Wk|Wv|Wo)^T
  unsigned short* qb  = (unsigned short*)(ws + (16u << 20)); // 24 MiB (Q | K | V^T)
  unsigned short* hsb = (unsigned short*)(ws + (40u << 20)); // 8 MiB (attn out)

  cast_bf16_kernel<<<2048, 256, 0, stream>>>(x, xb);
  transpose_cast_kernel<<<dim3(32, 32, 4), 256, 0, stream>>>(WQ, WK, WV, WO, wt);
  // fused QKV projection: N = 3072; Q pre-scaled; V^T via LDS-transposed epilogue
  gemm_bt_kernel<0><<<dim3(24, 32), 256, 0, stream>>>(
      xb, wt, (void*)qb, bQ, bK, bV, M_ROWS, 3072, DM);
  attn_kernel<<<1024, 256, 0, stream>>>(qb, qb + 4194304u, qb + 8388608u, hsb);
  // output projection: f32 out
  gemm_bt_kernel<1><<<dim3(8, 32), 256, 0, stream>>>(
      hsb, wt + 3u * 1048576u, d_out, bO, nullptr, nullptr, M_ROWS, DM, DM);
}

// Round 11
// 103.994 us; speedup vs baseline: 1.7833x; 1.1540x over previous
//
#include <hip/hip_runtime.h>
#include <hip/hip_bf16.h>

#define S_LEN 2048
#define NH 16
#define HD 64
#define DM 1024
#define BATCH 2
#define M_ROWS (BATCH * S_LEN)  // 4096
#define SCALE2 0.18033688011112043f  /* 0.125 * log2(e) */
#define M2FIX 8.0f

typedef float f32x4 __attribute__((ext_vector_type(4)));
typedef float f32x16 __attribute__((ext_vector_type(16)));
typedef __bf16 bf16x8 __attribute__((ext_vector_type(8)));
typedef short short8 __attribute__((ext_vector_type(8)));

__device__ __forceinline__ unsigned short f2bf(float f) {
  unsigned u = __builtin_bit_cast(unsigned, f);
  u += 0x7FFFu + ((u >> 16) & 1u);
  return (unsigned short)(u >> 16);
}

__device__ __forceinline__ f32x4 mfma16(bf16x8 a, bf16x8 b, f32x4 c) {
  return __builtin_amdgcn_mfma_f32_16x16x32_bf16(a, b, c, 0, 0, 0);
}

__device__ __forceinline__ f32x16 mfma32(bf16x8 a, bf16x8 b, f32x16 c) {
  return __builtin_amdgcn_mfma_f32_32x32x16_bf16(a, b, c, 0, 0, 0);
}

__device__ __forceinline__ void gload_lds16(const void* g, void* l) {
  __builtin_amdgcn_global_load_lds(
      (const __attribute__((address_space(1))) void*)g,
      (__attribute__((address_space(3))) void*)l, 16, 0, 0);
}

// ---------------- cast x -> bf16 (vectorized) ----------------
__global__ __launch_bounds__(256) void cast_bf16_kernel(
    const float* __restrict__ in, unsigned short* __restrict__ out) {
  int i = blockIdx.x * 256 + threadIdx.x;  // each handles 8 elems
  const float4* p = (const float4*)in;
  float4 f0 = p[i * 2], f1 = p[i * 2 + 1];
  short8 o;
  o[0] = (short)f2bf(f0.x); o[1] = (short)f2bf(f0.y);
  o[2] = (short)f2bf(f0.z); o[3] = (short)f2bf(f0.w);
  o[4] = (short)f2bf(f1.x); o[5] = (short)f2bf(f1.y);
  o[6] = (short)f2bf(f1.z); o[7] = (short)f2bf(f1.w);
  ((short8*)out)[i] = o;
}

// ---------------- transpose + cast weights: Wt[n][k] = bf16(W[k][n]) ----------------
__global__ __launch_bounds__(256) void transpose_cast_kernel(
    const float* __restrict__ W0, const float* __restrict__ W1,
    const float* __restrict__ W2, const float* __restrict__ W3,
    unsigned short* __restrict__ out) {
  int z = blockIdx.z;
  const float* W = (z == 0) ? W0 : (z == 1) ? W1 : (z == 2) ? W2 : W3;
  __shared__ float tile[32][33];
  int tx = threadIdx.x & 31, ty = threadIdx.x >> 5;  // 32 x 8
  int bx = blockIdx.x * 32, by = blockIdx.y * 32;
#pragma unroll
  for (int i = 0; i < 4; ++i)
    tile[ty + i * 8][tx] = W[(size_t)(by + ty + i * 8) * DM + bx + tx];
  __syncthreads();
  unsigned short* o = out + (size_t)z * DM * DM;
#pragma unroll
  for (int i = 0; i < 4; ++i)
    o[(size_t)(bx + ty + i * 8) * DM + by + tx] = f2bf(tile[tx][ty + i * 8]);
}

// ---------------- GEMM: C[m][n] = sum_k A[m][k] * Bt[n][k] --------------------
// Triple-buffered staging, counted vmcnt(4), one barrier per K-step.
// MODE 0: QKV fused (N=3072). Q pre-scaled by SCALE2; V written transposed per
//         head via LDS transpose: Vt[((b*16+h)*64+d)*2048 + s].
// MODE 1: f32 out (single buffer), bias0.
template <int MODE>
__global__ __launch_bounds__(256) void gemm_bt_kernel(
    const unsigned short* __restrict__ A, const unsigned short* __restrict__ Bt,
    void* __restrict__ Cptr, const float* __restrict__ bias0,
    const float* __restrict__ bias1, const float* __restrict__ bias2,
    int M, int N, int K) {
  __shared__ __align__(16) unsigned short Sbuf[2][3][4096];  // As | Bs (contiguous)
  unsigned short (*As)[4096] = Sbuf[0];
  unsigned short (*Bs)[4096] = Sbuf[1];
  const int t = threadIdx.x, lane = t & 63;
  const int wid = t >> 6, wr = wid >> 1, wc = wid & 1;
  const int r16 = lane & 15, g = lane >> 4;
  const int m0 = blockIdx.y * 128, n0 = blockIdx.x * 128;
  const int nk = K >> 5;

  const int n1 = t, n2 = t + 256;
  const int r1g = t >> 2, c1g = (t & 3) * 8;
  const int r2g = (t + 256) >> 2;

  const unsigned short* ap1 = A + (size_t)(m0 + r1g) * K + c1g;
  const unsigned short* ap2 = A + (size_t)(m0 + r2g) * K + c1g;
  const unsigned short* bp1 = Bt + (size_t)(n0 + r1g) * K + c1g;
  const unsigned short* bp2 = Bt + (size_t)(n0 + r2g) * K + c1g;

#define GSTAGE(s)                          \
  gload_lds16(ap1, &As[s][n1 * 8]);        \
  gload_lds16(bp1, &Bs[s][n1 * 8]);        \
  gload_lds16(ap2, &As[s][n2 * 8]);        \
  gload_lds16(bp2, &Bs[s][n2 * 8]);        \
  ap1 += 32; ap2 += 32; bp1 += 32; bp2 += 32;

  f32x4 acc[4][4] = {};

  GSTAGE(0);
  GSTAGE(1);

  for (int kt = 0; kt < nk; ++kt) {
    const int cs = kt % 3;
    if (kt + 1 < nk) {
      asm volatile("s_waitcnt vmcnt(4)" ::: "memory");
    } else {
      asm volatile("s_waitcnt vmcnt(0)" ::: "memory");
    }
    __builtin_amdgcn_s_barrier();
    if (kt + 2 < nk) { GSTAGE((kt + 2) % 3); }

    bf16x8 af[4], bfr[4];
#pragma unroll
    for (int mi = 0; mi < 4; ++mi)
      af[mi] = *(const bf16x8*)&As[cs][(wr * 64 + mi * 16 + r16) * 32 + g * 8];
#pragma unroll
    for (int ni = 0; ni < 4; ++ni)
      bfr[ni] = *(const bf16x8*)&Bs[cs][(wc * 64 + ni * 16 + r16) * 32 + g * 8];
    __builtin_amdgcn_s_setprio(1);
#pragma unroll
    for (int mi = 0; mi < 4; ++mi)
#pragma unroll
      for (int ni = 0; ni < 4; ++ni)
        acc[mi][ni] = mfma16(af[mi], bfr[ni], acc[mi][ni]);
    __builtin_amdgcn_s_setprio(0);
  }
#undef GSTAGE

  if (MODE == 0) {
    unsigned short* Cb = (unsigned short*)Cptr;
    const int buf = n0 >> 10;  // whole block lies in one of Q/K/V (128 | 1024)
    if (buf < 2) {
      const float* bp = buf ? bias1 : bias0;
      const float sc = buf ? 1.0f : SCALE2;  // pre-scale Q for attn
#pragma unroll
      for (int ni = 0; ni < 4; ++ni) {
        int cn = (n0 & 1023) + wc * 64 + ni * 16 + r16;
        float bv = bp[cn];
#pragma unroll
        for (int mi = 0; mi < 4; ++mi) {
          int rowb = m0 + wr * 64 + mi * 16 + 4 * g;
#pragma unroll
          for (int j = 0; j < 4; ++j)
            Cb[(size_t)buf * 4194304u + (size_t)(rowb + j) * 1024 + cn] =
                __builtin_bit_cast(unsigned short, (__bf16)((acc[mi][ni][j] + bv) * sc));
        }
      }
    } else {
      // V: transpose the 128(s) x 128(hd) tile through LDS, then write V^T with
      // 16B stores contiguous along s.
      unsigned short* T = &Sbuf[0][0][0];  // 24576 shorts >= 128*136 = 17408
      __syncthreads();  // all waves done with staging LDS
#pragma unroll
      for (int ni = 0; ni < 4; ++ni) {
        int cnl = wc * 64 + ni * 16 + r16;
        float bv = bias2[(n0 & 1023) + cnl];
#pragma unroll
        for (int mi = 0; mi < 4; ++mi) {
          int sl = wr * 64 + mi * 16 + 4 * g;
          union { __bf16 h4[4]; uint2 u; } cv;
#pragma unroll
          for (int j = 0; j < 4; ++j) cv.h4[j] = (__bf16)(acc[mi][ni][j] + bv);
          *(uint2*)&T[cnl * 136 + sl] = cv.u;
        }
      }
      __syncthreads();
      const int bb = m0 >> 11, s0g = m0 & 2047;
      unsigned short* Vt = Cb + 8388608u;
#pragma unroll
      for (int p = 0; p < 8; ++p) {
        int idx = p * 256 + t;
        int cnl = idx >> 4, sch = idx & 15;
        int cng = (n0 & 1023) + cnl;
        int hh = cng >> 6, d = cng & 63;
        short8 v = *(const short8*)&T[cnl * 136 + sch * 8];
        *(short8*)&Vt[(((size_t)((bb * 16 + hh) * 64 + d)) << 11) + s0g + sch * 8] = v;
      }
    }
  } else {
    float* Cf = (float*)Cptr;
#pragma unroll
    for (int ni = 0; ni < 4; ++ni) {
      int col = n0 + wc * 64 + ni * 16 + r16;
      float bv = bias0[col];
#pragma unroll
      for (int mi = 0; mi < 4; ++mi) {
        int rowb = m0 + wr * 64 + mi * 16 + 4 * g;
#pragma unroll
        for (int j = 0; j < 4; ++j)
          Cf[(size_t)(rowb + j) * N + col] = acc[mi][ni][j] + bv;
      }
    }
  }
}

// ---------------- flash attention v11: 32x32 MFMA, kv-split waves, reg-P -------------
// grid 512 x 256. Block = 64 q-rows; sequential halves {mq, 31-mq} -> uniform 17
// 128-wide kv iterations. Wave w owns kv quarter w*32 of each iteration and BOTH
// 32-q output tiles (K/V A-fragments shared across the two q-tiles -> DS/FLOP
// halved vs 16x16). P stays in registers: QK^T C-layout (col = q = lane&31) is
// converted to the PV B-operand layout with 4 permlane32_swap per q-tile.
// Cross-wave (kv) O-reduction through padded LDS once per half.
// Double-buffered K/V staging, vmcnt(0)+single barrier per iter (r8-proven).
// Fixed-shift exp2 softmax (m=8, exact). XCD decode keeps K/V L2-resident.
__global__ __launch_bounds__(256, 2) void attn_kernel(
    const unsigned short* __restrict__ Qm, const unsigned short* __restrict__ Km,
    const unsigned short* __restrict__ VtG, unsigned short* __restrict__ Om) {
  const int t = threadIdx.x, lane = t & 63, w = t >> 6;
  const int l31 = lane & 31, hi = lane >> 5;
  const int bid = blockIdx.x;
  const int xk = bid & 7, slot = bid >> 3;
  const int grp = xk * 4 + (slot >> 4);  // (b,h) group, 4 per XCD
  const int mq = slot & 15;
  const int h = grp & 15, b = grp >> 4;

  // LDS: [0,32K) = K dbuf (2 x 128kv x 64d), [32K,64K) = V^T dbuf (2 x 64d x 128kv)
  // overlay: reduce buffer R (4 waves x 64q x stride68 f32) + ls tail.
  __shared__ __align__(16) char LB[71680];
  float* R = (float*)LB;
  float* ls = (float*)(LB + 69632);

  const unsigned short* Kbase = Km + (size_t)(b * S_LEN) * DM + h * HD;
  const unsigned short* Vbase = VtG + (size_t)((b * NH + h) * HD) * S_LEN;

  // staging assignments (linear LDS dest, inverse-swizzled global source)
  const int kg = ((t & 7) ^ ((t >> 3) & 7)) * 8;    // K global chunk (elems)
  const int kr0 = t >> 3;                           // K row 0..31 (+32/pass)
  const int vg = ((t & 15) ^ ((t >> 4) & 15)) * 8;  // V global chunk (elems)
  const int vr0 = t >> 4;                           // V row 0..15 (+16/pass)

  auto stage = [&](int cs, int kv0) {
    unsigned short* kd = (unsigned short*)(LB + cs * 16384) + t * 8;
    unsigned short* vd = (unsigned short*)(LB + 32768 + cs * 16384) + t * 8;
#pragma unroll
    for (int p = 0; p < 4; ++p)
      gload_lds16(Kbase + (size_t)(kv0 + kr0 + 32 * p) * DM + kg, kd + 2048 * p);
#pragma unroll
    for (int p = 0; p < 4; ++p)
      gload_lds16(Vbase + (size_t)(vr0 + 16 * p) * S_LEN + kv0 + vg, vd + 2048 * p);
  };

  for (int half = 0; half < 2; ++half) {
    const int T = half ? 31 - mq : mq;  // 64-row q-tile index 0..31
    const int q0 = T * 64;

    // Q B-fragments (pre-scaled by SCALE2 in the GEMM epilogue)
    bf16x8 qfr[2][4];
#pragma unroll
    for (int qt = 0; qt < 2; ++qt) {
      const unsigned short* Qp =
          Qm + (size_t)(b * S_LEN + q0 + qt * 32 + l31) * DM + h * HD;
#pragma unroll
      for (int kc = 0; kc < 4; ++kc)
        qfr[qt][kc] = *(const bf16x8*)(Qp + kc * 16 + hi * 8);
    }

    f32x16 oacc[2][2] = {};  // [dt][qt], O^T partial over this wave's kv stream
    float lsum0 = 0.f, lsum1 = 0.f;
    const int ntk = (T >> 1) + 1;

    stage(0, 0);

    for (int kt = 0; kt < ntk; ++kt) {
      const int cs = kt & 1;
      asm volatile("s_waitcnt vmcnt(0)" ::: "memory");
      __builtin_amdgcn_s_barrier();
      if (kt + 1 < ntk) stage(cs ^ 1, (kt + 1) * 128);

      const int kv0w = kt * 128 + w * 32;  // this wave's kv base
      if (kv0w <= q0 + 63) {
        const unsigned short* Ksb = (const unsigned short*)(LB + cs * 16384);
        const unsigned short* Vsb = (const unsigned short*)(LB + 32768 + cs * 16384);

        // K A-fragments (shared across both q-tiles): row = w*32 + l31
        bf16x8 kf[4];
#pragma unroll
        for (int kc = 0; kc < 4; ++kc)
          kf[kc] = *(const bf16x8*)&Ksb[(w * 32 + l31) * 64 +
                                        (((hi + 2 * kc) ^ (lane & 7)) * 8)];
        bool act0 = false, act1 = false;
        bf16x8 pfr[2][2];
#pragma unroll
        for (int qt = 0; qt < 2; ++qt) {
          const bool act = (kv0w <= q0 + qt * 32 + 31);
          if (qt == 0) act0 = act; else act1 = act;
          if (!act) continue;
          // St[kv][q]: C col = q = l31, row = (r&3)+8*(r>>2)+4*hi
          f32x16 st = {};
          __builtin_amdgcn_s_setprio(1);
#pragma unroll
          for (int kc = 0; kc < 4; ++kc) st = mfma32(kf[kc], qfr[qt][kc], st);
          __builtin_amdgcn_s_setprio(0);

          const bool needmask = (kv0w + 31 > q0 + qt * 32);
          const int qg = q0 + qt * 32 + l31;
          float p[16];
          float ps = 0.f;
#pragma unroll
          for (int r = 0; r < 16; ++r) {
            int row = (r & 3) + 8 * (r >> 2) + 4 * hi;
            float v = __builtin_amdgcn_exp2f(st[r] - M2FIX);
            if (needmask && (kv0w + row > qg)) v = 0.f;
            p[r] = v;
            ps += v;
          }
          if (qt == 0) lsum0 += ps; else lsum1 += ps;

          // pack to bf16 pairs, then permlane32_swap -> PV B-operand layout
          unsigned pw[8];
#pragma unroll
          for (int r = 0; r < 8; ++r) {
            union { __bf16 h2[2]; unsigned u; } cv;
            cv.h2[0] = (__bf16)p[2 * r];
            cv.h2[1] = (__bf16)p[2 * r + 1];
            pw[r] = cv.u;
          }
          {
            auto s0 = __builtin_amdgcn_permlane32_swap(pw[0], pw[2], false, false);
            pw[0] = s0[0]; pw[2] = s0[1];
            auto s1 = __builtin_amdgcn_permlane32_swap(pw[1], pw[3], false, false);
            pw[1] = s1[0]; pw[3] = s1[1];
            auto s2 = __builtin_amdgcn_permlane32_swap(pw[4], pw[6], false, false);
            pw[4] = s2[0]; pw[6] = s2[1];
            auto s3 = __builtin_amdgcn_permlane32_swap(pw[5], pw[7], false, false);
            pw[5] = s3[0]; pw[7] = s3[1];
          }
          union { unsigned u[4]; bf16x8 v; } f0, f1;
          f0.u[0] = pw[0]; f0.u[1] = pw[1]; f0.u[2] = pw[2]; f0.u[3] = pw[3];
          f1.u[0] = pw[4]; f1.u[1] = pw[5]; f1.u[2] = pw[6]; f1.u[3] = pw[7];
          pfr[qt][0] = f0.v;
          pfr[qt][1] = f1.v;
        }

        // V^T A-fragments (shared across q-tiles): row d = dt*32 + l31
        bf16x8 vf[2][2];
#pragma unroll
        for (int dt = 0; dt < 2; ++dt)
#pragma unroll
          for (int ks = 0; ks < 2; ++ks)
            vf[dt][ks] = *(const bf16x8*)&Vsb[(dt * 32 + l31) * 128 +
                                              (((4 * w + 2 * ks + hi) ^ (lane & 15)) * 8)];
        __builtin_amdgcn_s_setprio(1);
        if (act0) {
#pragma unroll
          for (int dt = 0; dt < 2; ++dt) {
            oacc[dt][0] = mfma32(vf[dt][0], pfr[0][0], oacc[dt][0]);
            oacc[dt][0] = mfma32(vf[dt][1], pfr[0][1], oacc[dt][0]);
          }
        }
        if (act1) {
#pragma unroll
          for (int dt = 0; dt < 2; ++dt) {
            oacc[dt][1] = mfma32(vf[dt][0], pfr[1][0], oacc[dt][1]);
            oacc[dt][1] = mfma32(vf[dt][1], pfr[1][1], oacc[dt][1]);
          }
        }
        __builtin_amdgcn_s_setprio(0);
      }
    }

    // ---- cross-wave (kv) reduction: partials -> LDS, sum, normalize, store ----
    __syncthreads();  // staging reads done; safe to overlay R
    float* Rw = R + w * 4352;  // 64 q x stride 68
#pragma unroll
    for (int dt = 0; dt < 2; ++dt)
#pragma unroll
      for (int qt = 0; qt < 2; ++qt) {
        int q = qt * 32 + l31;
#pragma unroll
        for (int r = 0; r < 16; r += 2) {
          int d = dt * 32 + ((r & 3) + 8 * (r >> 2)) + 4 * hi;
          float2 v2;
          v2.x = oacc[dt][qt][r];
          v2.y = oacc[dt][qt][r + 1];
          *(float2*)&Rw[q * 68 + d] = v2;
        }
      }
    ls[(w * 64 + l31) * 2 + hi] = lsum0;
    ls[(w * 64 + 32 + l31) * 2 + hi] = lsum1;
    __syncthreads();

    const int rq = t >> 2, dq = (t & 3) * 16;
    f32x4 a0 = {}, a1 = {}, a2 = {}, a3 = {};
#pragma unroll
    for (int w4 = 0; w4 < 4; ++w4) {
      const float* Rb = R + w4 * 4352 + rq * 68 + dq;
      a0 += *(const f32x4*)&Rb[0];
      a1 += *(const f32x4*)&Rb[4];
      a2 += *(const f32x4*)&Rb[8];
      a3 += *(const f32x4*)&Rb[12];
    }
    float s = 0.f;
#pragma unroll
    for (int w4 = 0; w4 < 4; ++w4)
      s += ls[(w4 * 64 + rq) * 2] + ls[(w4 * 64 + rq) * 2 + 1];
    float li = 1.0f / s;
    unsigned short* op = Om + (size_t)(b * S_LEN + q0 + rq) * DM + h * HD + dq;
    union { __bf16 hh[8]; uint4 u; } o0, o1;
#pragma unroll
    for (int i = 0; i < 4; ++i) {
      o0.hh[i] = (__bf16)(a0[i] * li);
      o0.hh[4 + i] = (__bf16)(a1[i] * li);
      o1.hh[i] = (__bf16)(a2[i] * li);
      o1.hh[4 + i] = (__bf16)(a3[i] * li);
    }
    *(uint4*)op = o0.u;
    *(uint4*)(op + 8) = o1.u;
    __syncthreads();  // R free before next half's stage(0)
  }
}

extern "C" void kernel_launch(void* const* d_in, const int* in_sizes, int n_in,
                              void* d_out, int out_size, void* d_ws, size_t ws_size,
                              hipStream_t stream) {
  (void)in_sizes; (void)n_in; (void)out_size; (void)ws_size;
  const float* x  = (const float*)d_in[0];
  const float* WQ = (const float*)d_in[1];
  const float* WK = (const float*)d_in[2];
  const float* WV = (const float*)d_in[3];
  const float* WO = (const float*)d_in[4];
  const float* bQ = (const float*)d_in[5];
  const float* bK = (const float*)d_in[6];
  const float* bV = (const float*)d_in[7];
  const float* bO = (const float*)d_in[8];

  char* ws = (char*)d_ws;
  unsigned short* xb  = (unsigned short*)(ws);               // 8 MiB (x bf16)
  unsigned short* wt  = (unsigned short*)(ws + (8u << 20));  // 8 MiB (Wq|Wk|Wv|Wo)^T
  unsigned short* qb  = (unsigned short*)(ws + (16u << 20)); // 24 MiB (Q | K | V^T)
  unsigned short* hsb = (unsigned short*)(ws + (40u << 20)); // 8 MiB (attn out)

  cast_bf16_kernel<<<2048, 256, 0, stream>>>(x, xb);
  transpose_cast_kernel<<<dim3(32, 32, 4), 256, 0, stream>>>(WQ, WK, WV, WO, wt);
  // fused QKV projection: N = 3072; Q pre-scaled; V^T via LDS-transposed epilogue
  gemm_bt_kernel<0><<<dim3(24, 32), 256, 0, stream>>>(
      xb, wt, (void*)qb, bQ, bK, bV, M_ROWS, 3072, DM);
  attn_kernel<<<512, 256, 0, stream>>>(qb, qb + 4194304u, qb + 8388608u, hsb);
  // output projection: f32 out
  gemm_bt_kernel<1><<<dim3(8, 32), 256, 0, stream>>>(
      hsb, wt + 3u * 1048576u, d_out, bO, nullptr, nullptr, M_ROWS, DM, DM);
}